// Round 5
// baseline (2437.571 us; speedup 1.0000x reference)
//
#include <hip/hip_runtime.h>
#include <stdint.h>

// Round 5: 3 matrices per 960-thread block (15 waves).
// Evidence r1/r2/r4: resident waves/CU == one workgroup's waves regardless of
// VGPR/LDS headroom -> pack 3 independent 5-wave Sinkhorn groups per block to
// triple latency hiding. VGPR must stay <=128 (15 waves = 4/SIMD);
// __launch_bounds__(960) enforces the cap the compiler already chose at 320.
// Staging single-buffered (32KB/group): exposed chunk latency is covered by
// the other two groups' compute. LDS 3 x 36.6KB = 109.8KB.
//
//   prep kernel: MLP relu(W1 x + b1) @ W2 + b2 is piecewise-AFFINE in scalar x
//     -> interleaved {A,B}[33][200] coefficient table + 32 knots in d_ws.
//   per group (320 thr, 5 waves): K tile bf16-packed in 65 VGPRs/thread.
//     Thread (rg=8gw+rgl, cg) owns rows {40c+rg} x cols [cbase, cbase+csz).
//   Gumbel staged per group in 5 chunks of 40 rows (32,000 B) via
//     global_load_lds (6x16B + 1x4B per wave per chunk), wave-private rows.
//   Row pass  a_i = 1/(K b)_i : b packed bf16 pairs in LDS, 13 v_dot2_f32_bf16
//     per row, reduce over cg via dpp xor1/xor2 + ds_swizzle xor4.
//   Col pass  b_j = 1/(K^T a)_j: unpack+fma over own 5 rows, reduce over
//     rg-in-wave all-VALU (row_ror:8 + permlane16/32_swap), wave partials in
//     scr, 100 pair-threads/group combine + rcp + pack bf16 pair into bbp.
//   Loss: col pass with (a .* r), rec = b * sum, mean((ordered-rec)^2).

#define NN 200
#define NMAT 2560
#define NITER 20
#define MPB 3          // matrices per block
#define GRID ((NMAT + MPB - 1) / MPB)   // 854

// per-group LDS layout (u32 units)
#define STG_U32 8000   // 40 rows x 200 f32 staging
#define SCR_OFF 8000   // 1040 f32: [wave][cg][k2][2]
#define BBP_OFF 9040   // 104 u32 packed bf16 b-pairs
#define WRED_OFF 9144  // 2 f32 + pad
#define GRP_U32 9152   // 36,608 bytes per group
#define SM_U32 (3*GRP_U32)  // 109,824 bytes

typedef uint32_t u32;

__device__ __forceinline__ float blo(u32 u){ return __uint_as_float(u<<16); }
__device__ __forceinline__ float bhi(u32 u){ return __uint_as_float(u & 0xffff0000u); }
__device__ __forceinline__ u32 bpack(float lo, float hi){
  u32 a=__float_as_uint(lo); a += 0x7fffu + ((a>>16)&1u);
  u32 b=__float_as_uint(hi); b += 0x7fffu + ((b>>16)&1u);
  return (a>>16) | (b & 0xffff0000u);
}
__device__ __forceinline__ float dot2bf(u32 kp, u32 bp, float acc){
  asm("v_dot2_f32_bf16 %0, %1, %2, %0" : "+v"(acc) : "v"(kp), "v"(bp));
  return acc;
}
template<int CTRL>
__device__ __forceinline__ float dpp_add(float x){
  return x + __int_as_float(__builtin_amdgcn_update_dpp(0, __float_as_int(x), CTRL, 0xF, 0xF, true));
}
template<int PAT>
__device__ __forceinline__ float swz_add(float x){
  return x + __int_as_float(__builtin_amdgcn_ds_swizzle(__float_as_int(x), PAT));
}
__device__ __forceinline__ float pl16_add(float x){
#if __has_builtin(__builtin_amdgcn_permlane16_swap)
  auto r = __builtin_amdgcn_permlane16_swap(__float_as_uint(x), __float_as_uint(x), false, false);
  return __uint_as_float(r[0]) + __uint_as_float(r[1]);
#else
  return x + __shfl_xor(x, 16, 64);
#endif
}
__device__ __forceinline__ float pl32_add(float x){
#if __has_builtin(__builtin_amdgcn_permlane32_swap)
  auto r = __builtin_amdgcn_permlane32_swap(__float_as_uint(x), __float_as_uint(x), false, false);
  return __uint_as_float(r[0]) + __uint_as_float(r[1]);
#else
  return x + __shfl_xor(x, 32, 64);
#endif
}

// ---------------- prep: piecewise-affine MLP coefficients ------------------
// ws layout (f32): [0..32) knots (unsorted); [32..) AB[33][200][2] interleaved.
__global__ void __launch_bounds__(256)
prep_kernel(const float* __restrict__ W1, const float* __restrict__ b1,
            const float* __restrict__ W2, const float* __restrict__ b2,
            float* __restrict__ ws) {
  __shared__ float kn[32], sg[32], w1s[32], b1s[32];
  __shared__ int ord[32];
  const int tid = threadIdx.x;
  if (tid < 32) {
    const float w1 = W1[tid], bv = b1[tid];
    float knot, s;
    if (w1 != 0.f) { knot = -bv / w1; s = (w1 > 0.f) ? 1.f : -1.f; }
    else           { knot = (bv > 0.f) ? -1e30f : 1e30f; s = 1.f; }
    kn[tid] = knot; sg[tid] = s; w1s[tid] = w1; b1s[tid] = bv;
    ws[tid] = knot;
  }
  __syncthreads();
  if (tid < 32) {
    int rk = 0;
#pragma unroll
    for (int v = 0; v < 32; ++v) {
      const float kv = kn[v];
      rk += (kv < kn[tid] || (kv == kn[tid] && v < tid)) ? 1 : 0;
    }
    ord[rk] = tid;
  }
  __syncthreads();
  if (tid < NN) {
    float w2l[32];
#pragma unroll
    for (int u = 0; u < 32; ++u) w2l[u] = W2[tid*32 + u];
    float A = 0.f, Bv = b2[tid];
#pragma unroll
    for (int u = 0; u < 32; ++u)
      if (sg[u] < 0.f) { A += w2l[u]*w1s[u]; Bv += w2l[u]*b1s[u]; }
    float* AB = ws + 32;
    AB[(0*NN + tid)*2 + 0] = A;
    AB[(0*NN + tid)*2 + 1] = Bv;
    for (int s = 0; s < 32; ++s) {
      const int u = ord[s];
      A  += sg[u]*w2l[u]*w1s[u];
      Bv += sg[u]*w2l[u]*b1s[u];
      AB[((s+1)*NN + tid)*2 + 0] = A;
      AB[((s+1)*NN + tid)*2 + 1] = Bv;
    }
  }
}

// ---------------- main ------------------------------------------------------
__global__ void __launch_bounds__(960)
sinkhorn_main(const float* __restrict__ random_,    // [256*200]
              const float* __restrict__ ordered_t,  // [2560*200]
              const float* __restrict__ random_t,   // [2560*200]
              const float* __restrict__ gumbel,     // [2560*200*200]
              const float* __restrict__ ws,
              float* __restrict__ out) {
  extern __shared__ u32 sm[];

  const int tid  = threadIdx.x;
  const int w15  = tid >> 6;                        // 0..14
  const int g    = (w15 >= 10) ? 2 : (w15 >= 5 ? 1 : 0);
  const int gw   = w15 - 5*g;                       // wave in group 0..4
  const int gtid = tid - 320*g;                     // 0..319

  u32* gsm  = sm + g*GRP_U32;
  u32* stg  = gsm;
  float* scr = (float*)(gsm + SCR_OFF);
  u32* bbp  = gsm + BBP_OFF;
  float* wred = (float*)(gsm + WRED_OFF);

  const int mraw = blockIdx.x * MPB + g;
  const bool dup = (mraw >= NMAT);
  const int m    = dup ? (NMAT - 1) : mraw;
  const int bidx = m & 255;

  const int lane = tid & 63;
  const int cg   = lane & 7;          // bits 0-2
  const int rgl  = (lane >> 3) & 7;   // bits 3-5
  const int rg   = gw * 8 + rgl;      // 0..39; owns rows {40c + rg}
  const int cbase = 25*cg + (cg & 1); // {0,26,50,76,100,126,150,176}
  const int csz   = 26 - 2*(cg & 1);  // 26 even cg, 24 odd cg
  const int p0    = cbase >> 1;

  if (gtid < 104) bbp[gtid] = 0x3f803f80u;  // packed {1.0bf, 1.0bf}
  __syncthreads();

  float xr[5]; int ii[5];
#pragma unroll
  for (int r = 0; r < 5; ++r) {
    xr[r] = random_[bidx*NN + 40*r + rg];
    ii[r] = 0;
  }
  for (int u = 0; u < 32; ++u) {
    const float kn = ws[u];
#pragma unroll
    for (int r = 0; r < 5; ++r) ii[r] += (kn < xr[r]) ? 1 : 0;
  }

  const float* ABt = ws + 32;
  const char* gmat = (const char*)gumbel + (size_t)m * (NN*NN*4);

  u32 Kt[5][13];

  // ------- staged build: single buffer, wave-private rows ------------------
#pragma unroll
  for (int c = 0; c < 5; ++c) {
    const char* gsrc = gmat + c*32000 + gw*6400;
    u32* dst = stg + gw*1600;
#pragma unroll
    for (int i = 0; i < 6; ++i)
      __builtin_amdgcn_global_load_lds((const u32*)(gsrc + i*1024 + lane*16),
                                       dst + i*256, 16, 0, 0);
    __builtin_amdgcn_global_load_lds((const u32*)(gsrc + 6144 + lane*4),
                                     dst + 1536, 4, 0, 0);
    asm volatile("s_waitcnt vmcnt(0)" ::: "memory");
    const float x = xr[c];
    const float* ab = ABt + (size_t)(ii[c]*NN + cbase) * 2;
    const u32* gls = stg + rg*200 + cbase;
#pragma unroll
    for (int k = 0; k < 13; ++k) {
      u32 pk = 0;
      if (2*k < csz) {
        const float4 abv = *(const float4*)(ab + 4*k);   // {A0,B0,A1,B1}
        const float2 gv  = *(const float2*)(gls + 2*k);
        const float e0 = __expf(fmaf(x, abv.x, abv.y) + gv.x);
        const float e1 = __expf(fmaf(x, abv.z, abv.w) + gv.y);
        pk = bpack(e0, e1);
      }
      Kt[c][k] = pk;
    }
  }

  // pair-thread mapping: gtid<100 owns cols (2*gtid, 2*gtid+1)
  const bool isp = (gtid < 100);
  int pscr = 0;
  if (isp) {
    const int col = 2*gtid;
    int gq = col / 25;
    if (col < 25*gq + (gq&1)) --gq;
    pscr = gq*13 + ((col - (25*gq + (gq&1))) >> 1);
  }

  // ------- 20 multiplicative Sinkhorn iterations ---------------------------
  float a[5];
  float b0r = 1.f, b1r = 1.f;

  for (int it = 0; it < NITER; ++it) {
    // row pass: a = 1/(K b), b packed bf16
    u32 blp[13];
#pragma unroll
    for (int k = 0; k < 13; ++k) blp[k] = bbp[p0 + k];
#pragma unroll
    for (int r = 0; r < 5; ++r) {
      float acc = 0.f;
#pragma unroll
      for (int k = 0; k < 13; ++k) acc = dot2bf(Kt[r][k], blp[k], acc);
      acc = dpp_add<0xB1>(acc);    // xor1
      acc = dpp_add<0x4E>(acc);    // xor2
      acc = swz_add<0x101F>(acc);  // xor4
      a[r] = __builtin_amdgcn_rcpf(acc);
    }
    // col pass: b = 1/(K^T a)
#pragma unroll
    for (int k2 = 0; k2 < 13; ++k2) {
      float lo = 0.f, hi = 0.f;
#pragma unroll
      for (int r = 0; r < 5; ++r) {
        const u32 d = Kt[r][k2];
        lo = fmaf(blo(d), a[r], lo);
        hi = fmaf(bhi(d), a[r], hi);
      }
      lo = dpp_add<0x128>(lo); lo = pl16_add(lo); lo = pl32_add(lo);
      hi = dpp_add<0x128>(hi); hi = pl16_add(hi); hi = pl32_add(hi);
      if ((lane & 56) == 0)
        *(float2*)(scr + (gw*104 + cg*13 + k2)*2) = make_float2(lo, hi);
    }
    __syncthreads();
    if (isp) {
      float s0 = 0.f, s1 = 0.f;
#pragma unroll
      for (int ww = 0; ww < 5; ++ww) {
        const float2 v = *(const float2*)(scr + (ww*104 + pscr)*2);
        s0 += v.x; s1 += v.y;
      }
      b0r = __builtin_amdgcn_rcpf(s0);
      b1r = __builtin_amdgcn_rcpf(s1);
      bbp[gtid] = bpack(b0r, b1r);
    }
    __syncthreads();
  }

  // ------- loss: rec = b .* K^T(a .* r); mean((ordered - rec)^2) -----------
  float ar[5];
#pragma unroll
  for (int r = 0; r < 5; ++r)
    ar[r] = a[r] * random_t[m*NN + 40*r + rg];
#pragma unroll
  for (int k2 = 0; k2 < 13; ++k2) {
    float lo = 0.f, hi = 0.f;
#pragma unroll
    for (int r = 0; r < 5; ++r) {
      const u32 d = Kt[r][k2];
      lo = fmaf(blo(d), ar[r], lo);
      hi = fmaf(bhi(d), ar[r], hi);
    }
    lo = dpp_add<0x128>(lo); lo = pl16_add(lo); lo = pl32_add(lo);
    hi = dpp_add<0x128>(hi); hi = pl16_add(hi); hi = pl32_add(hi);
    if ((lane & 56) == 0)
      *(float2*)(scr + (gw*104 + cg*13 + k2)*2) = make_float2(lo, hi);
  }
  __syncthreads();
  float lacc = 0.f;
  if (isp) {
    float s0 = 0.f, s1 = 0.f;
#pragma unroll
    for (int ww = 0; ww < 5; ++ww) {
      const float2 v = *(const float2*)(scr + (ww*104 + pscr)*2);
      s0 += v.x; s1 += v.y;
    }
    const float2 ov = *(const float2*)(ordered_t + m*NN + 2*gtid);
    const float d0 = ov.x - b0r*s0;
    const float d1 = ov.y - b1r*s1;
    lacc = fmaf(d0, d0, d1*d1);
  }
  if (gw < 2) {
    lacc = dpp_add<0xB1>(lacc);
    lacc = dpp_add<0x4E>(lacc);
    lacc = swz_add<0x101F>(lacc);
    lacc = dpp_add<0x128>(lacc);
    lacc = pl16_add(lacc);
    lacc = pl32_add(lacc);
    if (lane == 0) wred[gw] = lacc;
  }
  __syncthreads();
  if (gtid == 0 && !dup)
    atomicAdd(out, (wred[0] + wred[1]) * (1.0f / 512000.0f));
}

extern "C" void kernel_launch(void* const* d_in, const int* in_sizes, int n_in,
                              void* d_out, int out_size, void* d_ws, size_t ws_size,
                              hipStream_t stream) {
  (void)in_sizes; (void)n_in; (void)ws_size; (void)out_size;
  const float* random_  = (const float*)d_in[0];
  const float* ordered  = (const float*)d_in[1];
  const float* random_t = (const float*)d_in[2];
  const float* gumbel   = (const float*)d_in[3];
  const float* W1 = (const float*)d_in[4];
  const float* b1 = (const float*)d_in[5];
  const float* W2 = (const float*)d_in[6];
  const float* b2 = (const float*)d_in[7];
  float* out = (float*)d_out;
  float* ws  = (float*)d_ws;   // needs 52,928 B

  const size_t smem = SM_U32 * sizeof(u32);  // 109,824 B
  hipFuncSetAttribute((const void*)sinkhorn_main,
                      hipFuncAttributeMaxDynamicSharedMemorySize, (int)smem);
  prep_kernel<<<1, 256, 0, stream>>>(W1, b1, W2, b2, ws);
  hipMemsetAsync(out, 0, sizeof(float), stream);
  sinkhorn_main<<<GRID, 960, smem, stream>>>(random_, ordered, random_t, gumbel, ws, out);
}

// Round 6
// 2437.185 us; speedup vs baseline: 1.0002x; 1.0002x over previous
//
#include <hip/hip_runtime.h>
#include <stdint.h>

// Round 6 = round 5 with the register allocation pinned.
// r5 failed because plain __launch_bounds__(960) let the allocator target the
// 64-VGPR/8-wave-per-EU tier and spill the 65-reg K tile (FETCH 3.6GB, WRITE
// 1.26GB, VALUBusy 9.7%). amdgpu_waves_per_eu(4,4) pins the budget to
// 512/4 = 128 VGPR — the tier r4 proved holds this body spill-free — while
// keeping the 15-wave workgroup residency that r5 demonstrated (occupancy 38%).
//
//   3 matrices per 960-thread block (15 waves), one 5-wave group per matrix.
//   prep kernel: MLP relu(W1 x + b1) @ W2 + b2 is piecewise-AFFINE in scalar x
//     -> interleaved {A,B}[33][200] coefficient table + 32 knots in d_ws.
//   per group (320 thr): K tile bf16-packed in 65 VGPRs/thread.
//     Thread (rg=8gw+rgl, cg) owns rows {40c+rg} x cols [cbase, cbase+csz).
//   Gumbel staged per group in 5 chunks of 40 rows (32,000 B) via
//     global_load_lds (6x16B + 1x4B per wave per chunk), wave-private rows.
//   Row pass  a_i = 1/(K b)_i : b packed bf16 pairs in LDS, 13 v_dot2_f32_bf16
//     per row, reduce over cg via dpp xor1/xor2 + ds_swizzle xor4.
//   Col pass  b_j = 1/(K^T a)_j: unpack+fma over own 5 rows, reduce over
//     rg-in-wave all-VALU (row_ror:8 + permlane16/32_swap), wave partials in
//     scr, 100 pair-threads/group combine + rcp + pack bf16 pair into bbp.
//   Loss: col pass with (a .* r), rec = b * sum, mean((ordered-rec)^2).

#define NN 200
#define NMAT 2560
#define NITER 20
#define MPB 3          // matrices per block
#define GRID ((NMAT + MPB - 1) / MPB)   // 854

// per-group LDS layout (u32 units)
#define STG_U32 8000   // 40 rows x 200 f32 staging
#define SCR_OFF 8000   // 1040 f32: [wave][cg][k2][2]
#define BBP_OFF 9040   // 104 u32 packed bf16 b-pairs
#define WRED_OFF 9144  // 2 f32 + pad
#define GRP_U32 9152   // 36,608 bytes per group
#define SM_U32 (3*GRP_U32)  // 109,824 bytes

typedef uint32_t u32;

__device__ __forceinline__ float blo(u32 u){ return __uint_as_float(u<<16); }
__device__ __forceinline__ float bhi(u32 u){ return __uint_as_float(u & 0xffff0000u); }
__device__ __forceinline__ u32 bpack(float lo, float hi){
  u32 a=__float_as_uint(lo); a += 0x7fffu + ((a>>16)&1u);
  u32 b=__float_as_uint(hi); b += 0x7fffu + ((b>>16)&1u);
  return (a>>16) | (b & 0xffff0000u);
}
__device__ __forceinline__ float dot2bf(u32 kp, u32 bp, float acc){
  asm("v_dot2_f32_bf16 %0, %1, %2, %0" : "+v"(acc) : "v"(kp), "v"(bp));
  return acc;
}
template<int CTRL>
__device__ __forceinline__ float dpp_add(float x){
  return x + __int_as_float(__builtin_amdgcn_update_dpp(0, __float_as_int(x), CTRL, 0xF, 0xF, true));
}
template<int PAT>
__device__ __forceinline__ float swz_add(float x){
  return x + __int_as_float(__builtin_amdgcn_ds_swizzle(__float_as_int(x), PAT));
}
__device__ __forceinline__ float pl16_add(float x){
#if __has_builtin(__builtin_amdgcn_permlane16_swap)
  auto r = __builtin_amdgcn_permlane16_swap(__float_as_uint(x), __float_as_uint(x), false, false);
  return __uint_as_float(r[0]) + __uint_as_float(r[1]);
#else
  return x + __shfl_xor(x, 16, 64);
#endif
}
__device__ __forceinline__ float pl32_add(float x){
#if __has_builtin(__builtin_amdgcn_permlane32_swap)
  auto r = __builtin_amdgcn_permlane32_swap(__float_as_uint(x), __float_as_uint(x), false, false);
  return __uint_as_float(r[0]) + __uint_as_float(r[1]);
#else
  return x + __shfl_xor(x, 32, 64);
#endif
}

// ---------------- prep: piecewise-affine MLP coefficients ------------------
// ws layout (f32): [0..32) knots (unsorted); [32..) AB[33][200][2] interleaved.
__global__ void __launch_bounds__(256)
prep_kernel(const float* __restrict__ W1, const float* __restrict__ b1,
            const float* __restrict__ W2, const float* __restrict__ b2,
            float* __restrict__ ws) {
  __shared__ float kn[32], sg[32], w1s[32], b1s[32];
  __shared__ int ord[32];
  const int tid = threadIdx.x;
  if (tid < 32) {
    const float w1 = W1[tid], bv = b1[tid];
    float knot, s;
    if (w1 != 0.f) { knot = -bv / w1; s = (w1 > 0.f) ? 1.f : -1.f; }
    else           { knot = (bv > 0.f) ? -1e30f : 1e30f; s = 1.f; }
    kn[tid] = knot; sg[tid] = s; w1s[tid] = w1; b1s[tid] = bv;
    ws[tid] = knot;
  }
  __syncthreads();
  if (tid < 32) {
    int rk = 0;
#pragma unroll
    for (int v = 0; v < 32; ++v) {
      const float kv = kn[v];
      rk += (kv < kn[tid] || (kv == kn[tid] && v < tid)) ? 1 : 0;
    }
    ord[rk] = tid;
  }
  __syncthreads();
  if (tid < NN) {
    float w2l[32];
#pragma unroll
    for (int u = 0; u < 32; ++u) w2l[u] = W2[tid*32 + u];
    float A = 0.f, Bv = b2[tid];
#pragma unroll
    for (int u = 0; u < 32; ++u)
      if (sg[u] < 0.f) { A += w2l[u]*w1s[u]; Bv += w2l[u]*b1s[u]; }
    float* AB = ws + 32;
    AB[(0*NN + tid)*2 + 0] = A;
    AB[(0*NN + tid)*2 + 1] = Bv;
    for (int s = 0; s < 32; ++s) {
      const int u = ord[s];
      A  += sg[u]*w2l[u]*w1s[u];
      Bv += sg[u]*w2l[u]*b1s[u];
      AB[((s+1)*NN + tid)*2 + 0] = A;
      AB[((s+1)*NN + tid)*2 + 1] = Bv;
    }
  }
}

// ---------------- main ------------------------------------------------------
__global__ void
__attribute__((amdgpu_flat_work_group_size(960, 960), amdgpu_waves_per_eu(4, 4)))
sinkhorn_main(const float* __restrict__ random_,    // [256*200]
              const float* __restrict__ ordered_t,  // [2560*200]
              const float* __restrict__ random_t,   // [2560*200]
              const float* __restrict__ gumbel,     // [2560*200*200]
              const float* __restrict__ ws,
              float* __restrict__ out) {
  extern __shared__ u32 sm[];

  const int tid  = threadIdx.x;
  const int w15  = tid >> 6;                        // 0..14
  const int g    = (w15 >= 10) ? 2 : (w15 >= 5 ? 1 : 0);
  const int gw   = w15 - 5*g;                       // wave in group 0..4
  const int gtid = tid - 320*g;                     // 0..319

  u32* gsm  = sm + g*GRP_U32;
  u32* stg  = gsm;
  float* scr = (float*)(gsm + SCR_OFF);
  u32* bbp  = gsm + BBP_OFF;
  float* wred = (float*)(gsm + WRED_OFF);

  const int mraw = blockIdx.x * MPB + g;
  const bool dup = (mraw >= NMAT);
  const int m    = dup ? (NMAT - 1) : mraw;
  const int bidx = m & 255;

  const int lane = tid & 63;
  const int cg   = lane & 7;          // bits 0-2
  const int rgl  = (lane >> 3) & 7;   // bits 3-5
  const int rg   = gw * 8 + rgl;      // 0..39; owns rows {40c + rg}
  const int cbase = 25*cg + (cg & 1); // {0,26,50,76,100,126,150,176}
  const int csz   = 26 - 2*(cg & 1);  // 26 even cg, 24 odd cg
  const int p0    = cbase >> 1;

  if (gtid < 104) bbp[gtid] = 0x3f803f80u;  // packed {1.0bf, 1.0bf}
  __syncthreads();

  float xr[5]; int ii[5];
#pragma unroll
  for (int r = 0; r < 5; ++r) {
    xr[r] = random_[bidx*NN + 40*r + rg];
    ii[r] = 0;
  }
  for (int u = 0; u < 32; ++u) {
    const float kn = ws[u];
#pragma unroll
    for (int r = 0; r < 5; ++r) ii[r] += (kn < xr[r]) ? 1 : 0;
  }

  const float* ABt = ws + 32;
  const char* gmat = (const char*)gumbel + (size_t)m * (NN*NN*4);

  u32 Kt[5][13];

  // ------- staged build: single buffer, wave-private rows ------------------
#pragma unroll
  for (int c = 0; c < 5; ++c) {
    const char* gsrc = gmat + c*32000 + gw*6400;
    u32* dst = stg + gw*1600;
#pragma unroll
    for (int i = 0; i < 6; ++i)
      __builtin_amdgcn_global_load_lds((const u32*)(gsrc + i*1024 + lane*16),
                                       dst + i*256, 16, 0, 0);
    __builtin_amdgcn_global_load_lds((const u32*)(gsrc + 6144 + lane*4),
                                     dst + 1536, 4, 0, 0);
    asm volatile("s_waitcnt vmcnt(0)" ::: "memory");
    const float x = xr[c];
    const float* ab = ABt + (size_t)(ii[c]*NN + cbase) * 2;
    const u32* gls = stg + rg*200 + cbase;
#pragma unroll
    for (int k = 0; k < 13; ++k) {
      u32 pk = 0;
      if (2*k < csz) {
        const float4 abv = *(const float4*)(ab + 4*k);   // {A0,B0,A1,B1}
        const float2 gv  = *(const float2*)(gls + 2*k);
        const float e0 = __expf(fmaf(x, abv.x, abv.y) + gv.x);
        const float e1 = __expf(fmaf(x, abv.z, abv.w) + gv.y);
        pk = bpack(e0, e1);
      }
      Kt[c][k] = pk;
    }
  }

  // pair-thread mapping: gtid<100 owns cols (2*gtid, 2*gtid+1)
  const bool isp = (gtid < 100);
  int pscr = 0;
  if (isp) {
    const int col = 2*gtid;
    int gq = col / 25;
    if (col < 25*gq + (gq&1)) --gq;
    pscr = gq*13 + ((col - (25*gq + (gq&1))) >> 1);
  }

  // ------- 20 multiplicative Sinkhorn iterations ---------------------------
  float a[5];
  float b0r = 1.f, b1r = 1.f;

  for (int it = 0; it < NITER; ++it) {
    // row pass: a = 1/(K b), b packed bf16
    u32 blp[13];
#pragma unroll
    for (int k = 0; k < 13; ++k) blp[k] = bbp[p0 + k];
#pragma unroll
    for (int r = 0; r < 5; ++r) {
      float acc = 0.f;
#pragma unroll
      for (int k = 0; k < 13; ++k) acc = dot2bf(Kt[r][k], blp[k], acc);
      acc = dpp_add<0xB1>(acc);    // xor1
      acc = dpp_add<0x4E>(acc);    // xor2
      acc = swz_add<0x101F>(acc);  // xor4
      a[r] = __builtin_amdgcn_rcpf(acc);
    }
    // col pass: b = 1/(K^T a)
#pragma unroll
    for (int k2 = 0; k2 < 13; ++k2) {
      float lo = 0.f, hi = 0.f;
#pragma unroll
      for (int r = 0; r < 5; ++r) {
        const u32 d = Kt[r][k2];
        lo = fmaf(blo(d), a[r], lo);
        hi = fmaf(bhi(d), a[r], hi);
      }
      lo = dpp_add<0x128>(lo); lo = pl16_add(lo); lo = pl32_add(lo);
      hi = dpp_add<0x128>(hi); hi = pl16_add(hi); hi = pl32_add(hi);
      if ((lane & 56) == 0)
        *(float2*)(scr + (gw*104 + cg*13 + k2)*2) = make_float2(lo, hi);
    }
    __syncthreads();
    if (isp) {
      float s0 = 0.f, s1 = 0.f;
#pragma unroll
      for (int ww = 0; ww < 5; ++ww) {
        const float2 v = *(const float2*)(scr + (ww*104 + pscr)*2);
        s0 += v.x; s1 += v.y;
      }
      b0r = __builtin_amdgcn_rcpf(s0);
      b1r = __builtin_amdgcn_rcpf(s1);
      bbp[gtid] = bpack(b0r, b1r);
    }
    __syncthreads();
  }

  // ------- loss: rec = b .* K^T(a .* r); mean((ordered - rec)^2) -----------
  float ar[5];
#pragma unroll
  for (int r = 0; r < 5; ++r)
    ar[r] = a[r] * random_t[m*NN + 40*r + rg];
#pragma unroll
  for (int k2 = 0; k2 < 13; ++k2) {
    float lo = 0.f, hi = 0.f;
#pragma unroll
    for (int r = 0; r < 5; ++r) {
      const u32 d = Kt[r][k2];
      lo = fmaf(blo(d), ar[r], lo);
      hi = fmaf(bhi(d), ar[r], hi);
    }
    lo = dpp_add<0x128>(lo); lo = pl16_add(lo); lo = pl32_add(lo);
    hi = dpp_add<0x128>(hi); hi = pl16_add(hi); hi = pl32_add(hi);
    if ((lane & 56) == 0)
      *(float2*)(scr + (gw*104 + cg*13 + k2)*2) = make_float2(lo, hi);
  }
  __syncthreads();
  float lacc = 0.f;
  if (isp) {
    float s0 = 0.f, s1 = 0.f;
#pragma unroll
    for (int ww = 0; ww < 5; ++ww) {
      const float2 v = *(const float2*)(scr + (ww*104 + pscr)*2);
      s0 += v.x; s1 += v.y;
    }
    const float2 ov = *(const float2*)(ordered_t + m*NN + 2*gtid);
    const float d0 = ov.x - b0r*s0;
    const float d1 = ov.y - b1r*s1;
    lacc = fmaf(d0, d0, d1*d1);
  }
  if (gw < 2) {
    lacc = dpp_add<0xB1>(lacc);
    lacc = dpp_add<0x4E>(lacc);
    lacc = swz_add<0x101F>(lacc);
    lacc = dpp_add<0x128>(lacc);
    lacc = pl16_add(lacc);
    lacc = pl32_add(lacc);
    if (lane == 0) wred[gw] = lacc;
  }
  __syncthreads();
  if (gtid == 0 && !dup)
    atomicAdd(out, (wred[0] + wred[1]) * (1.0f / 512000.0f));
}

extern "C" void kernel_launch(void* const* d_in, const int* in_sizes, int n_in,
                              void* d_out, int out_size, void* d_ws, size_t ws_size,
                              hipStream_t stream) {
  (void)in_sizes; (void)n_in; (void)ws_size; (void)out_size;
  const float* random_  = (const float*)d_in[0];
  const float* ordered  = (const float*)d_in[1];
  const float* random_t = (const float*)d_in[2];
  const float* gumbel   = (const float*)d_in[3];
  const float* W1 = (const float*)d_in[4];
  const float* b1 = (const float*)d_in[5];
  const float* W2 = (const float*)d_in[6];
  const float* b2 = (const float*)d_in[7];
  float* out = (float*)d_out;
  float* ws  = (float*)d_ws;   // needs 52,928 B

  const size_t smem = SM_U32 * sizeof(u32);  // 109,824 B
  hipFuncSetAttribute((const void*)sinkhorn_main,
                      hipFuncAttributeMaxDynamicSharedMemorySize, (int)smem);
  prep_kernel<<<1, 256, 0, stream>>>(W1, b1, W2, b2, ws);
  hipMemsetAsync(out, 0, sizeof(float), stream);
  sinkhorn_main<<<GRID, 960, smem, stream>>>(random_, ordered, random_t, gumbel, ws, out);
}

// Round 7
// 610.791 us; speedup vs baseline: 3.9908x; 3.9902x over previous
//
#include <hip/hip_runtime.h>
#include <stdint.h>

// Round 7: fit the 64-VGPR tier the allocator insists on (r5/r6 evidence:
// large-WG kernels get register-targeted to 64 and spill anything bigger).
// 640 threads = 10 waves = ONE matrix per WG; 80 row-groups x 8 col-groups.
// Thread (rg = 8w+rgl, cg) owns rows {80d + rg : d < nr} (nr=3 if rg<40 else 2)
// x cols [cbase, cbase+csz) as bf16 pairs: Kt[3][13] = 39 VGPRs.
// Build: 3 bands (80/80/40 rows); wave-private staging via global_load_lds
// (6x16B + 1x4B = 6400 B per wave per band, rows 8w..8w+7 contiguous),
// single 64 KB buffer, vmcnt(0) per band, no barriers.
// Row pass  a_i = 1/(K b)_i : k-outer, 3 dot2 per k, reduce over cg (bits 0-2:
//   dpp xor1/xor2 + ds_swizzle xor4), rcp.
// Col pass  b_j = 1/(K^T a)_j: unpack+fma over <=3 rows, reduce over rgl
//   (bits 3-5: row_ror8 + permlane16/32_swap), wave partials in scr[10][8][13],
//   100 pair-threads combine + rcp + pack bf16 pair into bbp.
// Loss: col pass with (a .* r), rec = b * sum, mean((ordered-rec)^2).

#define NN 200
#define NMAT 2560
#define NITER 20

// LDS layout (u32 units)
#define SCR_OFF 16000   // 2080 f32: [wave 10][cg 8][k2 13][2]
#define BBP_OFF 18080   // 104 u32 packed bf16 b-pairs
#define WRED_OFF 18184  // 2 f32 + pad
#define SM_U32 18192    // 72,768 bytes

typedef uint32_t u32;

__device__ __forceinline__ float blo(u32 u){ return __uint_as_float(u<<16); }
__device__ __forceinline__ float bhi(u32 u){ return __uint_as_float(u & 0xffff0000u); }
__device__ __forceinline__ u32 bpack(float lo, float hi){
  u32 a=__float_as_uint(lo); a += 0x7fffu + ((a>>16)&1u);
  u32 b=__float_as_uint(hi); b += 0x7fffu + ((b>>16)&1u);
  return (a>>16) | (b & 0xffff0000u);
}
__device__ __forceinline__ float dot2bf(u32 kp, u32 bp, float acc){
  asm("v_dot2_f32_bf16 %0, %1, %2, %0" : "+v"(acc) : "v"(kp), "v"(bp));
  return acc;
}
template<int CTRL>
__device__ __forceinline__ float dpp_add(float x){
  return x + __int_as_float(__builtin_amdgcn_update_dpp(0, __float_as_int(x), CTRL, 0xF, 0xF, true));
}
template<int PAT>
__device__ __forceinline__ float swz_add(float x){
  return x + __int_as_float(__builtin_amdgcn_ds_swizzle(__float_as_int(x), PAT));
}
__device__ __forceinline__ float pl16_add(float x){
#if __has_builtin(__builtin_amdgcn_permlane16_swap)
  auto r = __builtin_amdgcn_permlane16_swap(__float_as_uint(x), __float_as_uint(x), false, false);
  return __uint_as_float(r[0]) + __uint_as_float(r[1]);
#else
  return x + __shfl_xor(x, 16, 64);
#endif
}
__device__ __forceinline__ float pl32_add(float x){
#if __has_builtin(__builtin_amdgcn_permlane32_swap)
  auto r = __builtin_amdgcn_permlane32_swap(__float_as_uint(x), __float_as_uint(x), false, false);
  return __uint_as_float(r[0]) + __uint_as_float(r[1]);
#else
  return x + __shfl_xor(x, 32, 64);
#endif
}

// ---------------- prep: piecewise-affine MLP coefficients ------------------
// ws layout (f32): [0..32) knots (unsorted); [32..) AB[33][200][2] interleaved.
__global__ void __launch_bounds__(256)
prep_kernel(const float* __restrict__ W1, const float* __restrict__ b1,
            const float* __restrict__ W2, const float* __restrict__ b2,
            float* __restrict__ ws) {
  __shared__ float kn[32], sg[32], w1s[32], b1s[32];
  __shared__ int ord[32];
  const int tid = threadIdx.x;
  if (tid < 32) {
    const float w1 = W1[tid], bv = b1[tid];
    float knot, s;
    if (w1 != 0.f) { knot = -bv / w1; s = (w1 > 0.f) ? 1.f : -1.f; }
    else           { knot = (bv > 0.f) ? -1e30f : 1e30f; s = 1.f; }
    kn[tid] = knot; sg[tid] = s; w1s[tid] = w1; b1s[tid] = bv;
    ws[tid] = knot;
  }
  __syncthreads();
  if (tid < 32) {
    int rk = 0;
#pragma unroll
    for (int v = 0; v < 32; ++v) {
      const float kv = kn[v];
      rk += (kv < kn[tid] || (kv == kn[tid] && v < tid)) ? 1 : 0;
    }
    ord[rk] = tid;
  }
  __syncthreads();
  if (tid < NN) {
    float w2l[32];
#pragma unroll
    for (int u = 0; u < 32; ++u) w2l[u] = W2[tid*32 + u];
    float A = 0.f, Bv = b2[tid];
#pragma unroll
    for (int u = 0; u < 32; ++u)
      if (sg[u] < 0.f) { A += w2l[u]*w1s[u]; Bv += w2l[u]*b1s[u]; }
    float* AB = ws + 32;
    AB[(0*NN + tid)*2 + 0] = A;
    AB[(0*NN + tid)*2 + 1] = Bv;
    for (int s = 0; s < 32; ++s) {
      const int u = ord[s];
      A  += sg[u]*w2l[u]*w1s[u];
      Bv += sg[u]*w2l[u]*b1s[u];
      AB[((s+1)*NN + tid)*2 + 0] = A;
      AB[((s+1)*NN + tid)*2 + 1] = Bv;
    }
  }
}

// ---------------- main ------------------------------------------------------
__global__ void __launch_bounds__(640)
sinkhorn_main(const float* __restrict__ random_,    // [256*200]
              const float* __restrict__ ordered_t,  // [2560*200]
              const float* __restrict__ random_t,   // [2560*200]
              const float* __restrict__ gumbel,     // [2560*200*200]
              const float* __restrict__ ws,
              float* __restrict__ out) {
  extern __shared__ u32 sm[];
  u32* stg = sm;
  float* scr = (float*)(sm + SCR_OFF);
  u32* bbp = sm + BBP_OFF;
  float* wred = (float*)(sm + WRED_OFF);

  const int tid  = threadIdx.x;
  const int m    = blockIdx.x;
  const int bidx = m & 255;

  const int w    = tid >> 6;          // 0..9
  const int lane = tid & 63;
  const int cg   = lane & 7;          // bits 0-2
  const int rgl  = (lane >> 3) & 7;   // bits 3-5
  const int rg   = w * 8 + rgl;       // 0..79; owns rows {80d + rg : d < nr}
  const int nr   = (rg < 40) ? 3 : 2; // wave-uniform (w<5 <-> rg<40)
  const int cbase = 25*cg + (cg & 1); // {0,26,50,76,100,126,150,176}
  const int csz   = 26 - 2*(cg & 1);  // 26 even cg, 24 odd cg
  const int p0    = cbase >> 1;

  if (tid < 104) bbp[tid] = 0x3f803f80u;  // packed {1.0bf, 1.0bf}
  __syncthreads();

  float xr[3]; int ii[3];
#pragma unroll
  for (int d = 0; d < 3; ++d) { xr[d] = 0.f; ii[d] = 0; }
#pragma unroll
  for (int d = 0; d < 3; ++d)
    if (d < nr) xr[d] = random_[bidx*NN + 80*d + rg];
  for (int u = 0; u < 32; ++u) {
    const float kn = ws[u];
#pragma unroll
    for (int d = 0; d < 3; ++d) ii[d] += (kn < xr[d]) ? 1 : 0;
  }

  const float* ABt = ws + 32;
  const char* gmat = (const char*)gumbel + (size_t)m * (NN*NN*4);

  u32 Kt[3][13];

  // ------- build: 3 bands, wave-private staging, single buffer -------------
#pragma unroll
  for (int d = 0; d < 3; ++d) {
    if (d < nr) {
      const char* gsrc = gmat + d*64000 + w*6400;   // rows 80d+8w..+7, contiguous
      u32* dst = stg + w*1600;
#pragma unroll
      for (int i = 0; i < 6; ++i)
        __builtin_amdgcn_global_load_lds((const u32*)(gsrc + i*1024 + lane*16),
                                         dst + i*256, 16, 0, 0);
      __builtin_amdgcn_global_load_lds((const u32*)(gsrc + 6144 + lane*4),
                                       dst + 1536, 4, 0, 0);
      asm volatile("s_waitcnt vmcnt(0)" ::: "memory");
      const float x = xr[d];
      const float* ab = ABt + (size_t)(ii[d]*NN + cbase) * 2;
      const u32* gls = stg + w*1600 + rgl*200 + cbase;
#pragma unroll
      for (int k = 0; k < 13; ++k) {
        u32 pk = 0;
        if (2*k < csz) {
          const float4 abv = *(const float4*)(ab + 4*k);   // {A0,B0,A1,B1}
          const float2 gv  = *(const float2*)(gls + 2*k);
          const float e0 = __expf(fmaf(x, abv.x, abv.y) + gv.x);
          const float e1 = __expf(fmaf(x, abv.z, abv.w) + gv.y);
          pk = bpack(e0, e1);
        }
        Kt[d][k] = pk;
      }
    } else {
#pragma unroll
      for (int k = 0; k < 13; ++k) Kt[d][k] = 0;   // rg>=40: no band-2 row
    }
  }

  // pair-thread mapping: tid<100 owns cols (2*tid, 2*tid+1)
  const bool isp = (tid < 100);
  int pscr = 0;
  if (isp) {
    const int col = 2*tid;
    int gq = col / 25;
    if (col < 25*gq + (gq&1)) --gq;
    pscr = gq*13 + ((col - (25*gq + (gq&1))) >> 1);
  }

  // ------- 20 multiplicative Sinkhorn iterations ---------------------------
  float a0, a1, a2;
  float b0r = 1.f, b1r = 1.f;

  for (int it = 0; it < NITER; ++it) {
    // row pass: a = 1/(K b), b packed bf16, k-outer
    float c0 = 0.f, c1 = 0.f, c2 = 0.f;
#pragma unroll
    for (int k = 0; k < 13; ++k) {
      const u32 bp = bbp[p0 + k];
      c0 = dot2bf(Kt[0][k], bp, c0);
      c1 = dot2bf(Kt[1][k], bp, c1);
      c2 = dot2bf(Kt[2][k], bp, c2);
    }
    c0 = swz_add<0x101F>(dpp_add<0x4E>(dpp_add<0xB1>(c0)));
    c1 = swz_add<0x101F>(dpp_add<0x4E>(dpp_add<0xB1>(c1)));
    c2 = swz_add<0x101F>(dpp_add<0x4E>(dpp_add<0xB1>(c2)));
    a0 = __builtin_amdgcn_rcpf(c0);
    a1 = __builtin_amdgcn_rcpf(c1);
    a2 = (nr == 3) ? __builtin_amdgcn_rcpf(c2) : 0.f;  // safe: Kt[2]=0 -> 0*0

    // col pass: b = 1/(K^T a)
#pragma unroll
    for (int k2 = 0; k2 < 13; ++k2) {
      const u32 d0 = Kt[0][k2], d1 = Kt[1][k2], d2 = Kt[2][k2];
      float lo = blo(d0) * a0, hi = bhi(d0) * a0;
      lo = fmaf(blo(d1), a1, lo); hi = fmaf(bhi(d1), a1, hi);
      lo = fmaf(blo(d2), a2, lo); hi = fmaf(bhi(d2), a2, hi);
      lo = dpp_add<0x128>(lo); lo = pl16_add(lo); lo = pl32_add(lo);
      hi = dpp_add<0x128>(hi); hi = pl16_add(hi); hi = pl32_add(hi);
      if ((lane & 56) == 0)
        *(float2*)(scr + (w*104 + cg*13 + k2)*2) = make_float2(lo, hi);
    }
    __syncthreads();
    if (isp) {
      float s0 = 0.f, s1 = 0.f;
#pragma unroll
      for (int ww = 0; ww < 10; ++ww) {
        const float2 v = *(const float2*)(scr + (ww*104 + pscr)*2);
        s0 += v.x; s1 += v.y;
      }
      b0r = __builtin_amdgcn_rcpf(s0);
      b1r = __builtin_amdgcn_rcpf(s1);
      bbp[tid] = bpack(b0r, b1r);
    }
    __syncthreads();
  }

  // ------- loss: rec = b .* K^T(a .* r); mean((ordered - rec)^2) -----------
  float ar0 = a0 * random_t[m*NN + rg];
  float ar1 = a1 * random_t[m*NN + 80 + rg];
  float ar2 = (nr == 3) ? a2 * random_t[m*NN + 160 + rg] : 0.f;
#pragma unroll
  for (int k2 = 0; k2 < 13; ++k2) {
    const u32 d0 = Kt[0][k2], d1 = Kt[1][k2], d2 = Kt[2][k2];
    float lo = blo(d0) * ar0, hi = bhi(d0) * ar0;
    lo = fmaf(blo(d1), ar1, lo); hi = fmaf(bhi(d1), ar1, hi);
    lo = fmaf(blo(d2), ar2, lo); hi = fmaf(bhi(d2), ar2, hi);
    lo = dpp_add<0x128>(lo); lo = pl16_add(lo); lo = pl32_add(lo);
    hi = dpp_add<0x128>(hi); hi = pl16_add(hi); hi = pl32_add(hi);
    if ((lane & 56) == 0)
      *(float2*)(scr + (w*104 + cg*13 + k2)*2) = make_float2(lo, hi);
  }
  __syncthreads();
  float lacc = 0.f;
  if (isp) {
    float s0 = 0.f, s1 = 0.f;
#pragma unroll
    for (int ww = 0; ww < 10; ++ww) {
      const float2 v = *(const float2*)(scr + (ww*104 + pscr)*2);
      s0 += v.x; s1 += v.y;
    }
    const float2 ov = *(const float2*)(ordered_t + m*NN + 2*tid);
    const float d0 = ov.x - b0r*s0;
    const float d1 = ov.y - b1r*s1;
    lacc = fmaf(d0, d0, d1*d1);
  }
  if (w < 2) {
    lacc = dpp_add<0xB1>(lacc);
    lacc = dpp_add<0x4E>(lacc);
    lacc = swz_add<0x101F>(lacc);
    lacc = dpp_add<0x128>(lacc);
    lacc = pl16_add(lacc);
    lacc = pl32_add(lacc);
    if (lane == 0) wred[w] = lacc;
  }
  __syncthreads();
  if (tid == 0)
    atomicAdd(out, (wred[0] + wred[1]) * (1.0f / 512000.0f));
}

extern "C" void kernel_launch(void* const* d_in, const int* in_sizes, int n_in,
                              void* d_out, int out_size, void* d_ws, size_t ws_size,
                              hipStream_t stream) {
  (void)in_sizes; (void)n_in; (void)ws_size; (void)out_size;
  const float* random_  = (const float*)d_in[0];
  const float* ordered  = (const float*)d_in[1];
  const float* random_t = (const float*)d_in[2];
  const float* gumbel   = (const float*)d_in[3];
  const float* W1 = (const float*)d_in[4];
  const float* b1 = (const float*)d_in[5];
  const float* W2 = (const float*)d_in[6];
  const float* b2 = (const float*)d_in[7];
  float* out = (float*)d_out;
  float* ws  = (float*)d_ws;   // needs 52,928 B

  const size_t smem = SM_U32 * sizeof(u32);  // 72,768 B
  hipFuncSetAttribute((const void*)sinkhorn_main,
                      hipFuncAttributeMaxDynamicSharedMemorySize, (int)smem);
  prep_kernel<<<1, 256, 0, stream>>>(W1, b1, W2, b2, ws);
  hipMemsetAsync(out, 0, sizeof(float), stream);
  sinkhorn_main<<<NMAT, 640, smem, stream>>>(random_, ordered, random_t, gumbel, ws, out);
}